// Round 1
// baseline (486.444 us; speedup 1.0000x reference)
//
#include <hip/hip_runtime.h>

typedef __bf16 bf16;
typedef __bf16 bf16x8 __attribute__((ext_vector_type(8)));
typedef float f32x4 __attribute__((ext_vector_type(4)));

#define NN 8192

__device__ inline bf16x8 cvt8(float4 lo, float4 hi) {
  bf16x8 r;
  r[0] = (__bf16)lo.x; r[1] = (__bf16)lo.y; r[2] = (__bf16)lo.z; r[3] = (__bf16)lo.w;
  r[4] = (__bf16)hi.x; r[5] = (__bf16)hi.y; r[6] = (__bf16)hi.z; r[7] = (__bf16)hi.w;
  return r;
}

// ---------------- enc1: X1T[c][r] = relu(nodes @ We1 + be1)^T, bf16 [128][8192]
__global__ __launch_bounds__(256) void k_enc1(const float* __restrict__ nodes,
                                              const float* __restrict__ We1,
                                              const float* __restrict__ be1,
                                              bf16* __restrict__ X1T) {
  __shared__ float Ns[64 * 68];   // nodes tile [64 rows][64 f], stride 68 (16B-aligned float4)
  __shared__ bf16 Os[128 * 72];   // out tile transposed [128 c][64 r], stride 72
  int tid = threadIdx.x;
  int r0 = blockIdx.x * 64;
  // stage nodes tile (64x64 f32), float4 per thread iter
  for (int idx = tid; idx < 64 * 16; idx += 256) {
    int r = idx >> 4, c4 = (idx & 15) * 4;
    float4 v = *(const float4*)(nodes + (r0 + r) * 64 + c4);
    *(float4*)(&Ns[r * 68 + c4]) = v;
  }
  __syncthreads();
  int c = tid & 127, rb = tid >> 7;  // rb in {0,1}; rows r = rb + 2k
  float acc[32];
  float b = be1[c];
#pragma unroll
  for (int k = 0; k < 32; ++k) acc[k] = b;
  for (int f = 0; f < 64; ++f) {
    float wv = We1[f * 128 + c];
#pragma unroll
    for (int k = 0; k < 32; ++k)
      acc[k] = fmaf(Ns[(rb + 2 * k) * 68 + f], wv, acc[k]);
  }
#pragma unroll
  for (int k = 0; k < 32; ++k) {
    float v = acc[k] > 0.f ? acc[k] : 0.f;
    Os[c * 72 + rb + 2 * k] = (bf16)v;
  }
  __syncthreads();
  // coalesced copy out: 2 threads per column, 64B each
  int c2 = tid >> 1, h = tid & 1;
  const uint4* src = (const uint4*)(Os + c2 * 72 + h * 32);
  uint4* dst = (uint4*)(X1T + c2 * NN + r0 + h * 32);
  dst[0] = src[0]; dst[1] = src[1]; dst[2] = src[2]; dst[3] = src[3];
}

// ---------------- pass1: X2part[y] = A[:, y*4096:(y+1)*4096] @ X1[y-range]  (f32 out [2][8192][128])
// BM=32, BN=128, 8 waves x 16 cols, MFMA 16x16x32 bf16, A converted in registers.
__global__ __launch_bounds__(512) void k_pass1(const float* __restrict__ A,
                                               const bf16* __restrict__ X1T,
                                               float* __restrict__ X2part) {
  __shared__ bf16 Bs[128 * 72];  // [col][k] bf16, stride 72 elems (144 B, breaks bank aliasing)
  int tid = threadIdx.x;
  int lane = tid & 63, w = tid >> 6;
  int r0 = blockIdx.x * 32;
  int kbase = blockIdx.y * 4096;
  int col0 = w * 16;
  f32x4 acc0 = {0.f, 0.f, 0.f, 0.f}, acc1 = {0.f, 0.f, 0.f, 0.f};
  int rowA = r0 + (lane & 15);
  int klane = (lane >> 4) * 8;
  const float* pa0 = A + rowA * NN + kbase + klane;
  const float* pa1 = pa0 + 16 * NN;
  // staging mapping: 512 threads, 4 per column, 16 bf16 (32B) each
  int sc = tid >> 2, sq = tid & 3;
  const bf16* bsrc = X1T + sc * NN + kbase + sq * 16;
  bf16* bdst = Bs + sc * 72 + sq * 16;

  for (int kt = 0; kt < 4096; kt += 64) {
    uint4 v0 = *(const uint4*)(bsrc + kt);
    uint4 v1 = *(const uint4*)(bsrc + kt + 8);
    __syncthreads();
    *(uint4*)bdst = v0;
    *(uint4*)(bdst + 8) = v1;
    __syncthreads();
#pragma unroll
    for (int kc = 0; kc < 2; ++kc) {
      int kk = kt + kc * 32;
      float4 a0lo = *(const float4*)(pa0 + kk);
      float4 a0hi = *(const float4*)(pa0 + kk + 4);
      float4 a1lo = *(const float4*)(pa1 + kk);
      float4 a1hi = *(const float4*)(pa1 + kk + 4);
      bf16x8 a0 = cvt8(a0lo, a0hi);
      bf16x8 a1 = cvt8(a1lo, a1hi);
      bf16x8 bfrag = *(const bf16x8*)(Bs + (col0 + (lane & 15)) * 72 + kc * 32 + klane);
      acc0 = __builtin_amdgcn_mfma_f32_16x16x32_bf16(a0, bfrag, acc0, 0, 0, 0);
      acc1 = __builtin_amdgcn_mfma_f32_16x16x32_bf16(a1, bfrag, acc1, 0, 0, 0);
    }
  }
  float* out = X2part + blockIdx.y * (NN * 128);
#pragma unroll
  for (int i = 0; i < 4; ++i) {
    int rr = (lane >> 4) * 4 + i;
    out[(r0 + rr) * 128 + col0 + (lane & 15)] = acc0[i];
    out[(r0 + rr + 16) * 128 + col0 + (lane & 15)] = acc1[i];
  }
}

// ---------------- mid: X3T[c][r] = relu((X2p0+X2p1) @ We2 + be2)^T, bf16 [64][8192]
__global__ __launch_bounds__(256) void k_mid(const float* __restrict__ X2part,
                                             const float* __restrict__ We2,
                                             const float* __restrict__ be2,
                                             bf16* __restrict__ X3T) {
  __shared__ float X2s[64 * 128];  // broadcast-read, no pad needed
  __shared__ bf16 Os[64 * 72];
  int tid = threadIdx.x;
  int r0 = blockIdx.x * 64;
  const float* P0 = X2part;
  const float* P1 = X2part + NN * 128;
  for (int idx = tid; idx < 64 * 32; idx += 256) {
    int r = idx >> 5, c4 = (idx & 31) * 4;
    float4 u = *(const float4*)(P0 + (r0 + r) * 128 + c4);
    float4 v = *(const float4*)(P1 + (r0 + r) * 128 + c4);
    u.x += v.x; u.y += v.y; u.z += v.z; u.w += v.w;
    *(float4*)(&X2s[r * 128 + c4]) = u;
  }
  __syncthreads();
  int c = tid & 63, rb = tid >> 6;  // rb 0..3, rows rb + 4k
  float acc[16];
  float b = be2[c];
#pragma unroll
  for (int k = 0; k < 16; ++k) acc[k] = b;
  for (int j = 0; j < 128; ++j) {
    float wv = We2[j * 64 + c];
#pragma unroll
    for (int k = 0; k < 16; ++k)
      acc[k] = fmaf(X2s[(rb + 4 * k) * 128 + j], wv, acc[k]);
  }
#pragma unroll
  for (int k = 0; k < 16; ++k) {
    float v = acc[k] > 0.f ? acc[k] : 0.f;
    Os[c * 72 + rb + 4 * k] = (bf16)v;
  }
  __syncthreads();
  int c2 = tid >> 2, qq = tid & 3;
  const uint4* src = (const uint4*)(Os + c2 * 72 + qq * 16);
  uint4* dst = (uint4*)(X3T + c2 * NN + r0 + qq * 16);
  dst[0] = src[0]; dst[1] = src[1];
}

// ---------------- pass2: X4part[y] = A[:, y-range] @ X3[y-range] (f32 [2][8192][64])
// BM=32, BN=64: 8 waves = 4 col-groups x 2 k-groups; LDS reduce of the 2 k-groups.
__global__ __launch_bounds__(512) void k_pass2(const float* __restrict__ A,
                                               const bf16* __restrict__ X3T,
                                               float* __restrict__ X4part) {
  __shared__ bf16 Bs[64 * 72];
  __shared__ float X4s[2 * 32 * 68];
  int tid = threadIdx.x;
  int lane = tid & 63, w = tid >> 6;
  int r0 = blockIdx.x * 32;
  int kbase = blockIdx.y * 4096;
  int cw = w & 3, kg = w >> 2;
  int col0 = cw * 16;
  f32x4 acc0 = {0.f, 0.f, 0.f, 0.f}, acc1 = {0.f, 0.f, 0.f, 0.f};
  int rowA = r0 + (lane & 15);
  int klane = (lane >> 4) * 8;
  const float* pa0 = A + rowA * NN + kbase + kg * 32 + klane;
  const float* pa1 = pa0 + 16 * NN;
  int sc = tid >> 3, sq = tid & 7;  // 8 threads/col, 8 bf16 (16B) each
  const bf16* bsrc = X3T + sc * NN + kbase + sq * 8;
  bf16* bdst = Bs + sc * 72 + sq * 8;

  for (int kt = 0; kt < 4096; kt += 64) {
    uint4 v0 = *(const uint4*)(bsrc + kt);
    __syncthreads();
    *(uint4*)bdst = v0;
    __syncthreads();
    float4 a0lo = *(const float4*)(pa0 + kt);
    float4 a0hi = *(const float4*)(pa0 + kt + 4);
    float4 a1lo = *(const float4*)(pa1 + kt);
    float4 a1hi = *(const float4*)(pa1 + kt + 4);
    bf16x8 a0 = cvt8(a0lo, a0hi);
    bf16x8 a1 = cvt8(a1lo, a1hi);
    bf16x8 bfrag = *(const bf16x8*)(Bs + (col0 + (lane & 15)) * 72 + kg * 32 + klane);
    acc0 = __builtin_amdgcn_mfma_f32_16x16x32_bf16(a0, bfrag, acc0, 0, 0, 0);
    acc1 = __builtin_amdgcn_mfma_f32_16x16x32_bf16(a1, bfrag, acc1, 0, 0, 0);
  }
  // write both k-group partials to LDS, then reduce + store
#pragma unroll
  for (int i = 0; i < 4; ++i) {
    int rr = (lane >> 4) * 4 + i;
    X4s[kg * 32 * 68 + rr * 68 + col0 + (lane & 15)] = acc0[i];
    X4s[kg * 32 * 68 + (rr + 16) * 68 + col0 + (lane & 15)] = acc1[i];
  }
  __syncthreads();
  float* out = X4part + blockIdx.y * (NN * 64);
  for (int idx = tid; idx < 2048; idx += 512) {
    int r = idx >> 6, cc = idx & 63;
    out[(r0 + r) * 64 + cc] = X4s[r * 68 + cc] + X4s[32 * 68 + r * 68 + cc];
  }
}

// ---------------- head: q = ((relu(relu([X4@Weo+beo, act]@Wc1+bc1)@Wc2+bc2))@Wq+bq)
__global__ __launch_bounds__(256) void k_head(const float* __restrict__ X4part,
                                              const float* __restrict__ actions,
                                              const float* __restrict__ Weo,
                                              const float* __restrict__ beo,
                                              const float* __restrict__ Wc1,
                                              const float* __restrict__ bc1,
                                              const float* __restrict__ Wc2,
                                              const float* __restrict__ bc2,
                                              const float* __restrict__ Wq,
                                              const float* __restrict__ bq,
                                              float* __restrict__ q) {
  __shared__ float X4s[32 * 65];
  __shared__ float hs[32 * 81];    // [emb(64) | actions(16)] stride 81
  __shared__ float h1s[32 * 129];
  __shared__ float h2s[32 * 65];
  int tid = threadIdx.x;
  int r0 = blockIdx.x * 32;
  const float* P0 = X4part;
  const float* P1 = X4part + NN * 64;
  for (int idx = tid; idx < 2048; idx += 256) {
    int r = idx >> 6, c = idx & 63;
    X4s[r * 65 + c] = P0[(r0 + r) * 64 + c] + P1[(r0 + r) * 64 + c];
  }
  for (int idx = tid; idx < 512; idx += 256) {
    int r = idx >> 4, a = idx & 15;
    hs[r * 81 + 64 + a] = actions[(r0 + r) * 16 + a];
  }
  __syncthreads();
  {  // emb = X4 @ Weo + beo (no relu)
    int c = tid & 63, rb = tid >> 6;  // rows rb + 4k
    float acc[8];
    float b = beo[c];
#pragma unroll
    for (int k = 0; k < 8; ++k) acc[k] = b;
    for (int j = 0; j < 64; ++j) {
      float wv = Weo[j * 64 + c];
#pragma unroll
      for (int k = 0; k < 8; ++k)
        acc[k] = fmaf(X4s[(rb + 4 * k) * 65 + j], wv, acc[k]);
    }
#pragma unroll
    for (int k = 0; k < 8; ++k) hs[(rb + 4 * k) * 81 + c] = acc[k];
  }
  __syncthreads();
  {  // h1 = relu(h @ Wc1 + bc1), h [32][80], Wc1 [80][128]
    int c = tid & 127, rb = tid >> 7;  // rows rb + 2k
    float acc[16];
    float b = bc1[c];
#pragma unroll
    for (int k = 0; k < 16; ++k) acc[k] = b;
    for (int j = 0; j < 80; ++j) {
      float wv = Wc1[j * 128 + c];
#pragma unroll
      for (int k = 0; k < 16; ++k)
        acc[k] = fmaf(hs[(rb + 2 * k) * 81 + j], wv, acc[k]);
    }
#pragma unroll
    for (int k = 0; k < 16; ++k) {
      float v = acc[k] > 0.f ? acc[k] : 0.f;
      h1s[(rb + 2 * k) * 129 + c] = v;
    }
  }
  __syncthreads();
  {  // h2 = relu(h1 @ Wc2 + bc2)
    int c = tid & 63, rb = tid >> 6;
    float acc[8];
    float b = bc2[c];
#pragma unroll
    for (int k = 0; k < 8; ++k) acc[k] = b;
    for (int j = 0; j < 128; ++j) {
      float wv = Wc2[j * 64 + c];
#pragma unroll
      for (int k = 0; k < 8; ++k)
        acc[k] = fmaf(h1s[(rb + 4 * k) * 129 + j], wv, acc[k]);
    }
#pragma unroll
    for (int k = 0; k < 8; ++k) {
      float v = acc[k] > 0.f ? acc[k] : 0.f;
      h2s[(rb + 4 * k) * 65 + c] = v;
    }
  }
  __syncthreads();
  if (tid < 32) {  // q = h2 @ Wq + bq
    float acc = bq[0];
    for (int j = 0; j < 64; ++j) acc = fmaf(h2s[tid * 65 + j], Wq[j], acc);
    q[r0 + tid] = acc;
  }
}

extern "C" void kernel_launch(void* const* d_in, const int* in_sizes, int n_in,
                              void* d_out, int out_size, void* d_ws, size_t ws_size,
                              hipStream_t stream) {
  const float* nodes = (const float*)d_in[0];
  // d_in[1] = edges (unused by reference)
  const float* A = (const float*)d_in[2];
  const float* actions = (const float*)d_in[3];
  const float* We1 = (const float*)d_in[4];
  const float* be1 = (const float*)d_in[5];
  const float* We2 = (const float*)d_in[6];
  const float* be2 = (const float*)d_in[7];
  const float* Weo = (const float*)d_in[8];
  const float* beo = (const float*)d_in[9];
  const float* Wc1 = (const float*)d_in[10];
  const float* bc1 = (const float*)d_in[11];
  const float* Wc2 = (const float*)d_in[12];
  const float* bc2 = (const float*)d_in[13];
  const float* Wq = (const float*)d_in[14];
  const float* bq = (const float*)d_in[15];
  float* q = (float*)d_out;

  char* ws = (char*)d_ws;
  bf16* X1T = (bf16*)(ws);                      // 2 MB  [128][8192] bf16
  bf16* X3T = (bf16*)(ws + (2u << 20));         // 1 MB  [64][8192] bf16
  float* X2p = (float*)(ws + (3u << 20));       // 8 MB  [2][8192][128] f32
  float* X4p = (float*)(ws + (11u << 20));      // 4 MB  [2][8192][64] f32

  k_enc1<<<128, 256, 0, stream>>>(nodes, We1, be1, X1T);
  k_pass1<<<dim3(256, 2), 512, 0, stream>>>(A, X1T, X2p);
  k_mid<<<128, 256, 0, stream>>>(X2p, We2, be2, X3T);
  k_pass2<<<dim3(256, 2), 512, 0, stream>>>(A, X3T, X4p);
  k_head<<<256, 256, 0, stream>>>(X4p, actions, Weo, beo, Wc1, bc1, Wc2, bc2, Wq, bq, q);
}

// Round 2
// 247.034 us; speedup vs baseline: 1.9691x; 1.9691x over previous
//
#include <hip/hip_runtime.h>

typedef __bf16 bf16;
typedef __bf16 bf16x8 __attribute__((ext_vector_type(8)));
typedef float f32x4 __attribute__((ext_vector_type(4)));

#define NN 8192

__device__ inline bf16x8 cvt8(float4 lo, float4 hi) {
  bf16x8 r;
  r[0] = (__bf16)lo.x; r[1] = (__bf16)lo.y; r[2] = (__bf16)lo.z; r[3] = (__bf16)lo.w;
  r[4] = (__bf16)hi.x; r[5] = (__bf16)hi.y; r[6] = (__bf16)hi.z; r[7] = (__bf16)hi.w;
  return r;
}

// ---------------- enc1: B1p[k/32][c(128)][k&31] = relu(nodes @ We1 + be1) packed bf16
__global__ __launch_bounds__(256) void k_enc1(const float* __restrict__ nodes,
                                              const float* __restrict__ We1,
                                              const float* __restrict__ be1,
                                              bf16* __restrict__ B1p) {
  __shared__ float Ns[64 * 68];
  __shared__ bf16 Os[128 * 72];   // [col][row-in-block], stride 72
  int tid = threadIdx.x;
  int r0 = blockIdx.x * 64;
  for (int idx = tid; idx < 64 * 16; idx += 256) {
    int r = idx >> 4, c4 = (idx & 15) * 4;
    float4 v = *(const float4*)(nodes + (r0 + r) * 64 + c4);
    *(float4*)(&Ns[r * 68 + c4]) = v;
  }
  __syncthreads();
  int c = tid & 127, rb = tid >> 7;  // rows rb + 2k
  float acc[32];
  float b = be1[c];
#pragma unroll
  for (int k = 0; k < 32; ++k) acc[k] = b;
  for (int f = 0; f < 64; ++f) {
    float wv = We1[f * 128 + c];
#pragma unroll
    for (int k = 0; k < 32; ++k)
      acc[k] = fmaf(Ns[(rb + 2 * k) * 68 + f], wv, acc[k]);
  }
#pragma unroll
  for (int k = 0; k < 32; ++k) {
    float v = acc[k] > 0.f ? acc[k] : 0.f;
    Os[c * 72 + rb + 2 * k] = (bf16)v;
  }
  __syncthreads();
  // packed write: k-tile t = r0/32 + h, per col 32 contiguous bf16
  int c2 = tid >> 1, h = tid & 1;
  const uint4* src = (const uint4*)(Os + c2 * 72 + h * 32);
  uint4* dst = (uint4*)(B1p + (size_t)(r0 / 32 + h) * 128 * 32 + c2 * 32);
  dst[0] = src[0]; dst[1] = src[1]; dst[2] = src[2]; dst[3] = src[3];
}

// ---------------- pass: Out[part][r][c] = A[:, krange] @ Bpacked, no LDS, no barriers.
// Wave: M=32 rows, NCG*16 cols, K = KL per blockIdx.y. A f32 converted in regs.
struct AF { float4 q[4]; };

template <int NCG>
__global__ __launch_bounds__(256, 2) void k_pass(const float* __restrict__ A,
                                                 const bf16* __restrict__ Bp,
                                                 float* __restrict__ Out,
                                                 int KL) {
  constexpr int COLS = NCG * 16;
  int tid = threadIdx.x;
  int lane = tid & 63, w = tid >> 6;
  int l15 = lane & 15, lg = lane >> 4;
  int klane = lg * 8;
  int r0 = blockIdx.x * 128 + w * 32;
  int kbase = blockIdx.y * KL;
  const float* pa0 = A + (size_t)(r0 + l15) * NN + kbase + klane;
  const float* pa1 = pa0 + (size_t)16 * NN;
  const bf16* bbase = Bp + (size_t)(kbase >> 5) * COLS * 32 + (size_t)l15 * 32 + klane;

  f32x4 acc[2][NCG];
#pragma unroll
  for (int m = 0; m < 2; ++m)
#pragma unroll
    for (int cg = 0; cg < NCG; ++cg) acc[m][cg] = (f32x4){0.f, 0.f, 0.f, 0.f};

  auto LDA = [&](int kt, AF& f) {
    f.q[0] = *(const float4*)(pa0 + kt);
    f.q[1] = *(const float4*)(pa0 + kt + 4);
    f.q[2] = *(const float4*)(pa1 + kt);
    f.q[3] = *(const float4*)(pa1 + kt + 4);
  };
  auto LDB = [&](int kt, uint4* b) {
    const bf16* p = bbase + (size_t)(kt >> 5) * (COLS * 32);
#pragma unroll
    for (int cg = 0; cg < NCG; ++cg) b[cg] = *(const uint4*)(p + cg * 512);
  };
  auto CMP = [&](const AF& f, const uint4* b) {
    bf16x8 a0 = cvt8(f.q[0], f.q[1]);
    bf16x8 a1 = cvt8(f.q[2], f.q[3]);
#pragma unroll
    for (int cg = 0; cg < NCG; ++cg) {
      bf16x8 bfr = __builtin_bit_cast(bf16x8, b[cg]);
      acc[0][cg] = __builtin_amdgcn_mfma_f32_16x16x32_bf16(a0, bfr, acc[0][cg], 0, 0, 0);
      acc[1][cg] = __builtin_amdgcn_mfma_f32_16x16x32_bf16(a1, bfr, acc[1][cg], 0, 0, 0);
    }
  };

  AF a0f, a1f;
  uint4 b0[NCG], b1[NCG];
  LDA(0, a0f);
  int ktail = KL - 64;
  int kt = 0;
  for (; kt < ktail; kt += 64) {
    LDA(kt + 32, a1f);
    LDB(kt, b0);
    CMP(a0f, b0);
    LDA(kt + 64, a0f);
    LDB(kt + 32, b1);
    CMP(a1f, b1);
  }
  LDA(kt + 32, a1f);
  LDB(kt, b0);
  CMP(a0f, b0);
  LDB(kt + 32, b1);
  CMP(a1f, b1);

  float* out = Out + (size_t)blockIdx.y * NN * COLS;
#pragma unroll
  for (int m = 0; m < 2; ++m)
#pragma unroll
    for (int cg = 0; cg < NCG; ++cg)
#pragma unroll
      for (int i = 0; i < 4; ++i)
        out[(size_t)(r0 + m * 16 + lg * 4 + i) * COLS + cg * 16 + l15] = acc[m][cg][i];
}

// ---------------- mid: B3p[k/32][c(64)][k&31] = relu(sum_p X2p @ We2 + be2) packed bf16
__global__ __launch_bounds__(256) void k_mid(const float* __restrict__ X2p,
                                             const float* __restrict__ We2,
                                             const float* __restrict__ be2,
                                             bf16* __restrict__ B3p, int KS) {
  __shared__ float X2s[64 * 128];
  __shared__ bf16 Os[64 * 72];
  int tid = threadIdx.x;
  int r0 = blockIdx.x * 64;
  for (int idx = tid; idx < 64 * 32; idx += 256) {
    int r = idx >> 5, c4 = (idx & 31) * 4;
    float4 u = {0.f, 0.f, 0.f, 0.f};
    for (int p = 0; p < KS; ++p) {
      float4 v = *(const float4*)(X2p + (size_t)p * NN * 128 + (size_t)(r0 + r) * 128 + c4);
      u.x += v.x; u.y += v.y; u.z += v.z; u.w += v.w;
    }
    *(float4*)(&X2s[r * 128 + c4]) = u;
  }
  __syncthreads();
  int c = tid & 63, rb = tid >> 6;  // rows rb + 4k
  float acc[16];
  float b = be2[c];
#pragma unroll
  for (int k = 0; k < 16; ++k) acc[k] = b;
  for (int j = 0; j < 128; ++j) {
    float wv = We2[j * 64 + c];
#pragma unroll
    for (int k = 0; k < 16; ++k)
      acc[k] = fmaf(X2s[(rb + 4 * k) * 128 + j], wv, acc[k]);
  }
#pragma unroll
  for (int k = 0; k < 16; ++k) {
    float v = acc[k] > 0.f ? acc[k] : 0.f;
    Os[c * 72 + rb + 4 * k] = (bf16)v;
  }
  __syncthreads();
  int u = tid & 127, half = tid >> 7;
  int c2 = u >> 1, h = u & 1;
  const uint4* src = (const uint4*)(Os + c2 * 72 + h * 32 + half * 16);
  uint4* dst = (uint4*)(B3p + (size_t)(r0 / 32 + h) * 64 * 32 + c2 * 32 + half * 16);
  dst[0] = src[0]; dst[1] = src[1];
}

// ---------------- head: q = ((relu(relu([X4@Weo+beo, act]@Wc1+bc1)@Wc2+bc2))@Wq+bq)
__global__ __launch_bounds__(256) void k_head(const float* __restrict__ X4p,
                                              const float* __restrict__ actions,
                                              const float* __restrict__ Weo,
                                              const float* __restrict__ beo,
                                              const float* __restrict__ Wc1,
                                              const float* __restrict__ bc1,
                                              const float* __restrict__ Wc2,
                                              const float* __restrict__ bc2,
                                              const float* __restrict__ Wq,
                                              const float* __restrict__ bq,
                                              float* __restrict__ q, int KS) {
  __shared__ float X4s[32 * 65];
  __shared__ float hs[32 * 81];
  __shared__ float h1s[32 * 129];
  __shared__ float h2s[32 * 65];
  int tid = threadIdx.x;
  int r0 = blockIdx.x * 32;
  for (int idx = tid; idx < 2048; idx += 256) {
    int r = idx >> 6, c = idx & 63;
    float s = 0.f;
    for (int p = 0; p < KS; ++p)
      s += X4p[(size_t)p * NN * 64 + (size_t)(r0 + r) * 64 + c];
    X4s[r * 65 + c] = s;
  }
  for (int idx = tid; idx < 512; idx += 256) {
    int r = idx >> 4, a = idx & 15;
    hs[r * 81 + 64 + a] = actions[(r0 + r) * 16 + a];
  }
  __syncthreads();
  {  // emb = X4 @ Weo + beo
    int c = tid & 63, rb = tid >> 6;
    float acc[8];
    float b = beo[c];
#pragma unroll
    for (int k = 0; k < 8; ++k) acc[k] = b;
    for (int j = 0; j < 64; ++j) {
      float wv = Weo[j * 64 + c];
#pragma unroll
      for (int k = 0; k < 8; ++k)
        acc[k] = fmaf(X4s[(rb + 4 * k) * 65 + j], wv, acc[k]);
    }
#pragma unroll
    for (int k = 0; k < 8; ++k) hs[(rb + 4 * k) * 81 + c] = acc[k];
  }
  __syncthreads();
  {  // h1 = relu(h @ Wc1 + bc1)
    int c = tid & 127, rb = tid >> 7;
    float acc[16];
    float b = bc1[c];
#pragma unroll
    for (int k = 0; k < 16; ++k) acc[k] = b;
    for (int j = 0; j < 80; ++j) {
      float wv = Wc1[j * 128 + c];
#pragma unroll
      for (int k = 0; k < 16; ++k)
        acc[k] = fmaf(hs[(rb + 2 * k) * 81 + j], wv, acc[k]);
    }
#pragma unroll
    for (int k = 0; k < 16; ++k) {
      float v = acc[k] > 0.f ? acc[k] : 0.f;
      h1s[(rb + 2 * k) * 129 + c] = v;
    }
  }
  __syncthreads();
  {  // h2 = relu(h1 @ Wc2 + bc2)
    int c = tid & 63, rb = tid >> 6;
    float acc[8];
    float b = bc2[c];
#pragma unroll
    for (int k = 0; k < 8; ++k) acc[k] = b;
    for (int j = 0; j < 128; ++j) {
      float wv = Wc2[j * 64 + c];
#pragma unroll
      for (int k = 0; k < 8; ++k)
        acc[k] = fmaf(h1s[(rb + 4 * k) * 129 + j], wv, acc[k]);
    }
#pragma unroll
    for (int k = 0; k < 8; ++k) {
      float v = acc[k] > 0.f ? acc[k] : 0.f;
      h2s[(rb + 4 * k) * 65 + c] = v;
    }
  }
  __syncthreads();
  if (tid < 32) {
    float acc = bq[0];
    for (int j = 0; j < 64; ++j) acc = fmaf(h2s[tid * 65 + j], Wq[j], acc);
    q[r0 + tid] = acc;
  }
}

extern "C" void kernel_launch(void* const* d_in, const int* in_sizes, int n_in,
                              void* d_out, int out_size, void* d_ws, size_t ws_size,
                              hipStream_t stream) {
  const float* nodes = (const float*)d_in[0];
  const float* A = (const float*)d_in[2];
  const float* actions = (const float*)d_in[3];
  const float* We1 = (const float*)d_in[4];
  const float* be1 = (const float*)d_in[5];
  const float* We2 = (const float*)d_in[6];
  const float* be2 = (const float*)d_in[7];
  const float* Weo = (const float*)d_in[8];
  const float* beo = (const float*)d_in[9];
  const float* Wc1 = (const float*)d_in[10];
  const float* bc1 = (const float*)d_in[11];
  const float* Wc2 = (const float*)d_in[12];
  const float* bc2 = (const float*)d_in[13];
  const float* Wq = (const float*)d_in[14];
  const float* bq = (const float*)d_in[15];
  float* q = (float*)d_out;

  const size_t MB = 1ull << 20;
  int KS = 2;
  if (ws_size >= 3 * MB + 8 * 6 * MB) KS = 8;
  else if (ws_size >= 3 * MB + 4 * 6 * MB) KS = 4;

  char* ws = (char*)d_ws;
  bf16* B1p = (bf16*)(ws);                      // 2 MB packed [256][128][32]
  bf16* B3p = (bf16*)(ws + 2 * MB);             // 1 MB packed [256][64][32]
  float* X2p = (float*)(ws + 3 * MB);           // KS * 4 MB
  float* X4p = (float*)(ws + 3 * MB + (size_t)KS * 4 * MB);  // KS * 2 MB

  int KL = NN / KS;
  k_enc1<<<128, 256, 0, stream>>>(nodes, We1, be1, B1p);
  k_pass<8><<<dim3(64, KS), 256, 0, stream>>>(A, B1p, X2p, KL);
  k_mid<<<128, 256, 0, stream>>>(X2p, We2, be2, B3p, KS);
  k_pass<4><<<dim3(64, KS), 256, 0, stream>>>(A, B3p, X4p, KL);
  k_head<<<256, 256, 0, stream>>>(X4p, actions, Weo, beo, Wc1, bc1, Wc2, bc2, Wq, bq, q, KS);
}